// Round 19
// baseline (27.468 us; speedup 1.0000x reference)
//
#include <hip/hip_runtime.h>

typedef _Float16 f16x8 __attribute__((ext_vector_type(8)));
typedef float f32x16 __attribute__((ext_vector_type(16)));

#define TRUNC_VAL 2.0f
#define TPS 32     // A-tiles per segment (LDS-resident); NSEG = NT/TPS
#define NSEG 16    // segments for N=16384
#define WPB 4      // waves per block
#define BPT 4      // query (B) tiles per wave: 4 MFMAs per A-frag read

// ---------------------------------------------------------------------------
// R19 = R16 champion (26.99us, absmax 0.0) + ONE change: an empty asm with
// "+v" constraint pins each MFMA destination to arch-VGPRs ("v" class
// excludes AGPRs). Cycle model: algorithmic chamfer ~12us vs measured ~22us;
// the gap matches 16 v_accvgpr_read per MFMA (AGPR-allocated dst, the same
// mechanism R4/R6's counters proved at 88 VGPR). If regalloc already used
// VGPRs this is a no-op; if it used AGPRs, the fold's shuttle reads vanish.
// ~135 regs total — inside (256,2), occupancy unchanged. Values untouched
// -> absmax 0.0.
// Ledger: R5 ILP-4 (+23%), R8 BPT=4 (+7%), R16 TPS=32 (+6%). Nulls/negs:
// fences (R2,-3x), launch fusion (R3/R4), (256,1) (R6,-23%), zero-remat
// (R7), 4-wave/ILP-2 (R9), pruning family (R10-14, tail-bound), TPS=64 (R17).
//
// Fragment layout (verified, absmax 0.0):
//   v_mfma_f32_32x32x16_f16, lane l of tile t at frag[t*64+l],
//   row/col = l&31, k = 8*(l>>5)+i.  hi/lo fp16 split, ~22-bit precision:
//   A (target j): [xh yh zh | xh yh zh | xl yl zl | wh wl | 0...] w=-0.5||y||^2
//   B (query  i): [xh yh zh | xl yl zl | xh yh zh | 1  1  | 0...]
//   => dot = q.y - 0.5||y||^2
// ---------------------------------------------------------------------------
__global__ __launch_bounds__(64 * WPB, 2) void chamfer_mfma_kernel(
    const float* __restrict__ fw, const float* __restrict__ bwv,
    const float* __restrict__ p0, const float* __restrict__ p1,
    float* __restrict__ Pfw, float* __restrict__ Pbw,
    float* __restrict__ out, int N) {
    __shared__ f16x8 Alds[TPS * 64];           // 32 KB: the block's A segment

    int lane = threadIdx.x & 63;
    int wave = threadIdx.x >> 6;
    int r    = lane & 31;
    bool hi  = lane >= 32;
    int col  = blockIdx.x * WPB + wave;        // query column: 128 queries/wave
    int seg  = blockIdx.y;                     // target segment (block-shared)
    int z    = blockIdx.z;
    float* __restrict__ P = z ? Pbw : Pfw;

    // out[0] = 0 once per launch; stream-ordered before reduce's atomicAdds.
    if (threadIdx.x == 0 && blockIdx.x == 0 && blockIdx.y == 0 && z == 0)
        out[0] = 0.0f;

    // ---- build B fragments in registers (once per wave) ----
    f16x8 b[BPT];
    #pragma unroll
    for (int c = 0; c < BPT; ++c) {
        int i = (col * BPT + c) * 32 + r;
        float qx = p0[3*i]   + fw[3*i];
        float qy = p0[3*i+1] + fw[3*i+1];
        float qz = p0[3*i+2] + fw[3*i+2];
        if (z) { qx -= bwv[3*i]; qy -= bwv[3*i+1]; qz -= bwv[3*i+2]; }
        _Float16 xh = (_Float16)qx, yh = (_Float16)qy, zh = (_Float16)qz;
        _Float16 xl = (_Float16)(qx - (float)xh);
        _Float16 yl = (_Float16)(qy - (float)yh);
        _Float16 zl = (_Float16)(qz - (float)zh);
        f16x8 o;
        if (!hi) { o[0]=xh; o[1]=yh; o[2]=zh; o[3]=xl; o[4]=yl; o[5]=zl; o[6]=xh; o[7]=yh; }
        else {
            o[0]=zh; o[1]=(_Float16)1.0f; o[2]=(_Float16)1.0f;
            o[3]=(_Float16)0.0f; o[4]=(_Float16)0.0f; o[5]=(_Float16)0.0f;
            o[6]=(_Float16)0.0f; o[7]=(_Float16)0.0f;
        }
        b[c] = o;
    }

    // ---- build A fragments into LDS (each wave packs TPS/WPB = 8 tiles) ----
    const float* __restrict__ tgt = z ? p0 : p1;
    #pragma unroll
    for (int lt = 0; lt < TPS / WPB; ++lt) {
        int t = wave * (TPS / WPB) + lt;
        int j = (seg * TPS + t) * 32 + r;
        float x = tgt[3*j], y = tgt[3*j+1], zc = tgt[3*j+2];
        _Float16 xh = (_Float16)x, yh = (_Float16)y, zh = (_Float16)zc;
        _Float16 xl = (_Float16)(x  - (float)xh);
        _Float16 yl = (_Float16)(y  - (float)yh);
        _Float16 zl = (_Float16)(zc - (float)zh);
        float w = -0.5f * (x*x + y*y + zc*zc);
        _Float16 wh = (_Float16)w, wl = (_Float16)(w - (float)wh);
        f16x8 o;
        if (!hi) { o[0]=xh; o[1]=yh; o[2]=zh; o[3]=xh; o[4]=yh; o[5]=zh; o[6]=xl; o[7]=yl; }
        else {
            o[0]=zl; o[1]=wh; o[2]=wl;
            o[3]=(_Float16)0.0f; o[4]=(_Float16)0.0f; o[5]=(_Float16)0.0f;
            o[6]=(_Float16)0.0f; o[7]=(_Float16)0.0f;
        }
        Alds[t * 64 + lane] = o;
    }
    __syncthreads();

    // ---- MFMA loop: 4 independent MFMAs in flight, then fold ----
    float m[BPT][4];
    #pragma unroll
    for (int c = 0; c < BPT; ++c)
        #pragma unroll
        for (int p = 0; p < 4; ++p) m[c][p] = -3.0e38f;

    const f32x16 zero = {};
    f16x8 a = Alds[lane];

#define FOLD(c, d)                                                  \
    _Pragma("unroll")                                               \
    for (int p = 0; p < 4; ++p) {                                   \
        m[c][p] = fmaxf(fmaxf(m[c][p], d[4*p  ]), d[4*p+1]);        \
        m[c][p] = fmaxf(fmaxf(m[c][p], d[4*p+2]), d[4*p+3]);        \
    }

    for (int t = 0; t < TPS; ++t) {
        f16x8 a_cur = a;
        int tn = (t + 1 < TPS) ? t + 1 : t;
        a = Alds[tn * 64 + lane];              // prefetch next A-frag
        f32x16 d0 = __builtin_amdgcn_mfma_f32_32x32x16_f16(a_cur, b[0], zero, 0, 0, 0);
        f32x16 d1 = __builtin_amdgcn_mfma_f32_32x32x16_f16(a_cur, b[1], zero, 0, 0, 0);
        f32x16 d2 = __builtin_amdgcn_mfma_f32_32x32x16_f16(a_cur, b[2], zero, 0, 0, 0);
        f32x16 d3 = __builtin_amdgcn_mfma_f32_32x32x16_f16(a_cur, b[3], zero, 0, 0, 0);
        // Pin the MFMA results to arch-VGPRs ("v" excludes AGPRs): if
        // regalloc had parked them in AGPRs, the folds below were paying
        // 16 v_accvgpr_read per MFMA (the R4/R6-diagnosed shuttle).
        asm volatile("" : "+v"(d0), "+v"(d1), "+v"(d2), "+v"(d3));
        FOLD(0, d0) FOLD(1, d1) FOLD(2, d2) FOLD(3, d3)
    }
#undef FOLD

    #pragma unroll
    for (int c = 0; c < BPT; ++c) {
        float v = fmaxf(fmaxf(m[c][0], m[c][1]), fmaxf(m[c][2], m[c][3]));
        v = fmaxf(v, __shfl_xor(v, 32, 64));   // fold the two row-halves
        if (lane < 32) P[(size_t)seg * N + col * (32 * BPT) + c * 32 + lane] = v;
    }
}

// ---------------------------------------------------------------------------
// Combine segment maxima, form truncated chamfer per query, mean-reduce.
// ---------------------------------------------------------------------------
__global__ __launch_bounds__(256) void reduce_kernel(
    const float* __restrict__ fw, const float* __restrict__ bwv,
    const float* __restrict__ p0,
    const float* __restrict__ Pfw, const float* __restrict__ Pbw,
    float* __restrict__ out, int N, float inv) {
    int z = blockIdx.z;
    const float* __restrict__ part = z ? Pbw : Pfw;

    int i = blockIdx.x * blockDim.x + threadIdx.x;
    float c = 0.0f;
    if (i < N) {
        float qx = p0[3*i]   + fw[3*i];
        float qy = p0[3*i+1] + fw[3*i+1];
        float qz = p0[3*i+2] + fw[3*i+2];
        if (z) { qx -= bwv[3*i]; qy -= bwv[3*i+1]; qz -= bwv[3*i+2]; }
        float q2 = qx*qx + qy*qy + qz*qz;
        float mv = -3.0e38f;
        #pragma unroll
        for (int s = 0; s < NSEG; ++s) mv = fmaxf(mv, part[(size_t)s * N + i]);
        float d2 = fmaf(-2.0f, mv, q2);        // ||q||^2 - 2*max = min sq dist
        d2 = fmaxf(d2, 0.0f);
        c = fminf(d2, TRUNC_VAL);
    }
    #pragma unroll
    for (int off = 32; off > 0; off >>= 1) c += __shfl_down(c, off, 64);
    __shared__ float wsum[256 / 64];
    int lane = threadIdx.x & 63, wid = threadIdx.x >> 6;
    if (lane == 0) wsum[wid] = c;
    __syncthreads();
    if (threadIdx.x == 0) {
        float s = 0.0f;
        #pragma unroll
        for (int w = 0; w < 256 / 64; ++w) s += wsum[w];
        atomicAdd(out, s * inv);
    }
}

extern "C" void kernel_launch(void* const* d_in, const int* in_sizes, int n_in,
                              void* d_out, int out_size, void* d_ws, size_t ws_size,
                              hipStream_t stream) {
    const float* fw  = (const float*)d_in[0];  // fw_flow_pred [N,3]
    const float* bwv = (const float*)d_in[1];  // bw_flow_pred [N,3]
    const float* p0  = (const float*)d_in[2];  // pcl_0 [N,3]
    const float* p1  = (const float*)d_in[3];  // pcl_1 [M,3]
    int N = in_sizes[0] / 3;                   // 16384; M == N for this problem
    int ncol = N / (32 * BPT);                 // 128 query columns

    float* out = (float*)d_out;
    char* w = (char*)d_ws;
    float* Pfw = (float*)w;                    w += (size_t)NSEG * N * 4;
    float* Pbw = (float*)w;

    dim3 grid(ncol / WPB, NSEG, 2);            // (32, 16, 2) = 1024 blocks
    chamfer_mfma_kernel<<<grid, 64 * WPB, 0, stream>>>(
        fw, bwv, p0, p1, Pfw, Pbw, out, N);

    dim3 rgrid((N + 255) / 256, 1, 2);
    reduce_kernel<<<rgrid, 256, 0, stream>>>(
        fw, bwv, p0, Pfw, Pbw, out, N, 1.0f / N);
}

// Round 20
// 27.032 us; speedup vs baseline: 1.0161x; 1.0161x over previous
//
#include <hip/hip_runtime.h>

typedef _Float16 f16x8 __attribute__((ext_vector_type(8)));
typedef float f32x16 __attribute__((ext_vector_type(16)));

#define TRUNC_VAL 2.0f
#define TPS 32     // A-tiles per segment (LDS-resident); NSEG = NT/TPS
#define NSEG 16    // segments for N=16384
#define WPB 4      // waves per block
#define BPT 4      // query (B) tiles per wave: 4 MFMAs per A-frag read

// ---------------------------------------------------------------------------
// FINAL = R16, the measured optimum (26.99us; reproduced 27.24 (R18),
// 27.47 (R19 null-pin variant); absmax 0.0 every round).
// Session ledger (39.9 -> 27.0us, -32%):
//   WINS: R4 fused pack (2-kernel), R5 ILP-4 named accumulators (+23%),
//         R8 BPT=4 off the 256-reg allocation boundary (+7%),
//         R16 TPS=32 prologue/P-traffic amortization (+6%).
//   NULLS/NEGATIVES (all counter-diagnosed): device-scope fences (R2, -3x),
//         launch-count fusion (R3/R4), (256,1) -> 88-VGPR AGPR-shuttle
//         schedule (R6, -23%), opaque-zero barrier (R7), 4-wave/ILP-2 (R9),
//         spatial-pruning family (R10-R14, best 51us: 76% of MEAN work
//         pruned but per-wave MAX work unpruned -> tail-bound),
//         TPS=64 (R17, 64KB LDS fill serializes behind the barrier),
//         "+v" AGPR pin on MFMA destinations (R19, null -> dst already VGPR).
// Ceiling note (not a roofline claim): matrix-pipe floor ~7us, serial
// MFMA+VALU ~11us, measured chamfer ~21-22us at 2 waves/SIMD; the residual
// is distributed issue/latency inefficiency that no HIP-source knob in the
// R5-R19 scan moved. MfmaUtil ~15% -> schedule-bound fixed point.
//
// Fragment layout (verified, absmax 0.0):
//   v_mfma_f32_32x32x16_f16, lane l of tile t at frag[t*64+l],
//   row/col = l&31, k = 8*(l>>5)+i.  hi/lo fp16 split, ~22-bit precision:
//   A (target j): [xh yh zh | xh yh zh | xl yl zl | wh wl | 0...] w=-0.5||y||^2
//   B (query  i): [xh yh zh | xl yl zl | xh yh zh | 1  1  | 0...]
//   => dot = q.y - 0.5||y||^2
// ---------------------------------------------------------------------------
__global__ __launch_bounds__(64 * WPB, 2) void chamfer_mfma_kernel(
    const float* __restrict__ fw, const float* __restrict__ bwv,
    const float* __restrict__ p0, const float* __restrict__ p1,
    float* __restrict__ Pfw, float* __restrict__ Pbw,
    float* __restrict__ out, int N) {
    __shared__ f16x8 Alds[TPS * 64];           // 32 KB: the block's A segment

    int lane = threadIdx.x & 63;
    int wave = threadIdx.x >> 6;
    int r    = lane & 31;
    bool hi  = lane >= 32;
    int col  = blockIdx.x * WPB + wave;        // query column: 128 queries/wave
    int seg  = blockIdx.y;                     // target segment (block-shared)
    int z    = blockIdx.z;
    float* __restrict__ P = z ? Pbw : Pfw;

    // out[0] = 0 once per launch; stream-ordered before reduce's atomicAdds.
    if (threadIdx.x == 0 && blockIdx.x == 0 && blockIdx.y == 0 && z == 0)
        out[0] = 0.0f;

    // ---- build B fragments in registers (once per wave) ----
    f16x8 b[BPT];
    #pragma unroll
    for (int c = 0; c < BPT; ++c) {
        int i = (col * BPT + c) * 32 + r;
        float qx = p0[3*i]   + fw[3*i];
        float qy = p0[3*i+1] + fw[3*i+1];
        float qz = p0[3*i+2] + fw[3*i+2];
        if (z) { qx -= bwv[3*i]; qy -= bwv[3*i+1]; qz -= bwv[3*i+2]; }
        _Float16 xh = (_Float16)qx, yh = (_Float16)qy, zh = (_Float16)qz;
        _Float16 xl = (_Float16)(qx - (float)xh);
        _Float16 yl = (_Float16)(qy - (float)yh);
        _Float16 zl = (_Float16)(qz - (float)zh);
        f16x8 o;
        if (!hi) { o[0]=xh; o[1]=yh; o[2]=zh; o[3]=xl; o[4]=yl; o[5]=zl; o[6]=xh; o[7]=yh; }
        else {
            o[0]=zh; o[1]=(_Float16)1.0f; o[2]=(_Float16)1.0f;
            o[3]=(_Float16)0.0f; o[4]=(_Float16)0.0f; o[5]=(_Float16)0.0f;
            o[6]=(_Float16)0.0f; o[7]=(_Float16)0.0f;
        }
        b[c] = o;
    }

    // ---- build A fragments into LDS (each wave packs TPS/WPB = 8 tiles) ----
    const float* __restrict__ tgt = z ? p0 : p1;
    #pragma unroll
    for (int lt = 0; lt < TPS / WPB; ++lt) {
        int t = wave * (TPS / WPB) + lt;
        int j = (seg * TPS + t) * 32 + r;
        float x = tgt[3*j], y = tgt[3*j+1], zc = tgt[3*j+2];
        _Float16 xh = (_Float16)x, yh = (_Float16)y, zh = (_Float16)zc;
        _Float16 xl = (_Float16)(x  - (float)xh);
        _Float16 yl = (_Float16)(y  - (float)yh);
        _Float16 zl = (_Float16)(zc - (float)zh);
        float w = -0.5f * (x*x + y*y + zc*zc);
        _Float16 wh = (_Float16)w, wl = (_Float16)(w - (float)wh);
        f16x8 o;
        if (!hi) { o[0]=xh; o[1]=yh; o[2]=zh; o[3]=xh; o[4]=yh; o[5]=zh; o[6]=xl; o[7]=yl; }
        else {
            o[0]=zl; o[1]=wh; o[2]=wl;
            o[3]=(_Float16)0.0f; o[4]=(_Float16)0.0f; o[5]=(_Float16)0.0f;
            o[6]=(_Float16)0.0f; o[7]=(_Float16)0.0f;
        }
        Alds[t * 64 + lane] = o;
    }
    __syncthreads();

    // ---- MFMA loop: 4 independent MFMAs in flight, then fold ----
    float m[BPT][4];
    #pragma unroll
    for (int c = 0; c < BPT; ++c)
        #pragma unroll
        for (int p = 0; p < 4; ++p) m[c][p] = -3.0e38f;

    const f32x16 zero = {};
    f16x8 a = Alds[lane];

#define FOLD(c, d)                                                  \
    _Pragma("unroll")                                               \
    for (int p = 0; p < 4; ++p) {                                   \
        m[c][p] = fmaxf(fmaxf(m[c][p], d[4*p  ]), d[4*p+1]);        \
        m[c][p] = fmaxf(fmaxf(m[c][p], d[4*p+2]), d[4*p+3]);        \
    }

    for (int t = 0; t < TPS; ++t) {
        f16x8 a_cur = a;
        int tn = (t + 1 < TPS) ? t + 1 : t;
        a = Alds[tn * 64 + lane];              // prefetch next A-frag
        f32x16 d0 = __builtin_amdgcn_mfma_f32_32x32x16_f16(a_cur, b[0], zero, 0, 0, 0);
        f32x16 d1 = __builtin_amdgcn_mfma_f32_32x32x16_f16(a_cur, b[1], zero, 0, 0, 0);
        f32x16 d2 = __builtin_amdgcn_mfma_f32_32x32x16_f16(a_cur, b[2], zero, 0, 0, 0);
        f32x16 d3 = __builtin_amdgcn_mfma_f32_32x32x16_f16(a_cur, b[3], zero, 0, 0, 0);
        FOLD(0, d0) FOLD(1, d1) FOLD(2, d2) FOLD(3, d3)
    }
#undef FOLD

    #pragma unroll
    for (int c = 0; c < BPT; ++c) {
        float v = fmaxf(fmaxf(m[c][0], m[c][1]), fmaxf(m[c][2], m[c][3]));
        v = fmaxf(v, __shfl_xor(v, 32, 64));   // fold the two row-halves
        if (lane < 32) P[(size_t)seg * N + col * (32 * BPT) + c * 32 + lane] = v;
    }
}

// ---------------------------------------------------------------------------
// Combine segment maxima, form truncated chamfer per query, mean-reduce.
// ---------------------------------------------------------------------------
__global__ __launch_bounds__(256) void reduce_kernel(
    const float* __restrict__ fw, const float* __restrict__ bwv,
    const float* __restrict__ p0,
    const float* __restrict__ Pfw, const float* __restrict__ Pbw,
    float* __restrict__ out, int N, float inv) {
    int z = blockIdx.z;
    const float* __restrict__ part = z ? Pbw : Pfw;

    int i = blockIdx.x * blockDim.x + threadIdx.x;
    float c = 0.0f;
    if (i < N) {
        float qx = p0[3*i]   + fw[3*i];
        float qy = p0[3*i+1] + fw[3*i+1];
        float qz = p0[3*i+2] + fw[3*i+2];
        if (z) { qx -= bwv[3*i]; qy -= bwv[3*i+1]; qz -= bwv[3*i+2]; }
        float q2 = qx*qx + qy*qy + qz*qz;
        float mv = -3.0e38f;
        #pragma unroll
        for (int s = 0; s < NSEG; ++s) mv = fmaxf(mv, part[(size_t)s * N + i]);
        float d2 = fmaf(-2.0f, mv, q2);        // ||q||^2 - 2*max = min sq dist
        d2 = fmaxf(d2, 0.0f);
        c = fminf(d2, TRUNC_VAL);
    }
    #pragma unroll
    for (int off = 32; off > 0; off >>= 1) c += __shfl_down(c, off, 64);
    __shared__ float wsum[256 / 64];
    int lane = threadIdx.x & 63, wid = threadIdx.x >> 6;
    if (lane == 0) wsum[wid] = c;
    __syncthreads();
    if (threadIdx.x == 0) {
        float s = 0.0f;
        #pragma unroll
        for (int w = 0; w < 256 / 64; ++w) s += wsum[w];
        atomicAdd(out, s * inv);
    }
}

extern "C" void kernel_launch(void* const* d_in, const int* in_sizes, int n_in,
                              void* d_out, int out_size, void* d_ws, size_t ws_size,
                              hipStream_t stream) {
    const float* fw  = (const float*)d_in[0];  // fw_flow_pred [N,3]
    const float* bwv = (const float*)d_in[1];  // bw_flow_pred [N,3]
    const float* p0  = (const float*)d_in[2];  // pcl_0 [N,3]
    const float* p1  = (const float*)d_in[3];  // pcl_1 [M,3]
    int N = in_sizes[0] / 3;                   // 16384; M == N for this problem
    int ncol = N / (32 * BPT);                 // 128 query columns

    float* out = (float*)d_out;
    char* w = (char*)d_ws;
    float* Pfw = (float*)w;                    w += (size_t)NSEG * N * 4;
    float* Pbw = (float*)w;

    dim3 grid(ncol / WPB, NSEG, 2);            // (32, 16, 2) = 1024 blocks
    chamfer_mfma_kernel<<<grid, 64 * WPB, 0, stream>>>(
        fw, bwv, p0, p1, Pfw, Pbw, out, N);

    dim3 rgrid((N + 255) / 256, 1, 2);
    reduce_kernel<<<rgrid, 256, 0, stream>>>(
        fw, bwv, p0, Pfw, Pbw, out, N, 1.0f / N);
}